// Round 8
// baseline (113.476 us; speedup 1.0000x reference)
//
#include <hip/hip_runtime.h>
#include <hip/hip_bf16.h>

// Problem: B=4096, D_IN=D_H=K=1024.
//   x = input_ @ fq(Wi,4).T + bi ; h = hidden @ fq(Wr,4).T + br
//   out = tanh(LN(x) + LN(h))
// ws layout:
//   +0      : bmax f32[512] (per-block weight absmax; 0..255 Wi, 256..511 Wr)
//   +2048   : scales f32[2] (si, sr) written by quant_k
//   +4096   : Qi  bf16 ints, 2 MB
//   +2M+4096: Qr  bf16 ints, 2 MB
//   +4M+4096: Xq  bf16 (x pre-LN, unscaled), 8 MB
//   +12M+..: Hq  bf16 (h pre-LN, unscaled), 8 MB

typedef float  f32x4  __attribute__((ext_vector_type(4)));
typedef __bf16 bf16x8 __attribute__((ext_vector_type(8)));
typedef __bf16 bf16x4 __attribute__((ext_vector_type(4)));

#define KDIM 1024

// ---------------- weight absmax (per-block partial max) ----------------
__global__ __launch_bounds__(256)
void absmax_k(const float* __restrict__ Wi, const float* __restrict__ Wr,
              float* __restrict__ bmax)
{
    const int b = blockIdx.x, t = threadIdx.x;
    const int tensor = b >> 8;
    const float* W = tensor ? Wr : Wi;
    const int lane = t & 63, wid = t >> 6;
    const f32x4* p = (const f32x4*)W;
    const size_t base = (size_t)(b & 255) * 1024;
    float m = 0.f;
#pragma unroll
    for (int k = 0; k < 4; ++k) {
        f32x4 v = p[base + k * 256 + t];
        m = fmaxf(m, fmaxf(fmaxf(fabsf(v[0]), fabsf(v[1])),
                           fmaxf(fabsf(v[2]), fabsf(v[3]))));
    }
#pragma unroll
    for (int o = 32; o >= 1; o >>= 1) m = fmaxf(m, __shfl_xor(m, o));
    __shared__ float wm_[4];
    if (lane == 0) wm_[wid] = m;
    __syncthreads();
    if (t == 0) bmax[b] = fmaxf(fmaxf(wm_[0], wm_[1]), fmaxf(wm_[2], wm_[3]));
}

// ---------------- quantize weights to integer bf16 (reduces bmax per block) ----------------
__global__ __launch_bounds__(256)
void quant_k(const float* __restrict__ Wi, const float* __restrict__ Wr,
             const float* __restrict__ bmax, float* __restrict__ scales,
             __bf16* __restrict__ Qi, __bf16* __restrict__ Qr)
{
    const int tensor = blockIdx.x >> 8;
    const int b = blockIdx.x & 255;
    const int t = threadIdx.x;
    const int lane = t & 63, wid = t >> 6;

    float m = bmax[tensor * 256 + t];
#pragma unroll
    for (int o = 32; o >= 1; o >>= 1) m = fmaxf(m, __shfl_xor(m, o));
    __shared__ float wm_[4];
    if (lane == 0) wm_[wid] = m;
    __syncthreads();
    m = fmaxf(fmaxf(wm_[0], wm_[1]), fmaxf(wm_[2], wm_[3]));
    const float s = m / 7.0f;
    if (t == 0 && b == 0) scales[tensor] = s;

    const float* W = tensor ? Wr : Wi;
    __bf16* Q = tensor ? Qr : Qi;
#pragma unroll
    for (int j = 0; j < 2; ++j) {
        const int e = b * 4096 + (j * 256 + t) * 8;
        f32x4 v0 = ((const f32x4*)(W + e))[0];
        f32x4 v1 = ((const f32x4*)(W + e))[1];
        bf16x8 o;
#pragma unroll
        for (int i = 0; i < 4; ++i) {
            o[i]     = (__bf16)rintf(v0[i] / s);
            o[i + 4] = (__bf16)rintf(v1[i] / s);
        }
        *(bf16x8*)(Q + e) = o;
    }
}

// ---------------- dual bf16 MFMA GEMM: 256x128 tile, 8 waves, NO LDS ----------------
// All operands L2-resident (B tile 256 KB, A stripe 1 MB f32). Each MFMA
// fragment is 16B contiguous per lane -> load global->reg directly.
// No LDS, no barriers, no lgkmcnt: waves free-run. Per iteration kt:
//   [issue A-f32(kt+1): 16 dwordx4] [issue B(kt+1): 8 dwordx4 -> bF[(kt+1)&1]]
//   [32 MFMA on aC(kt), bF[kt&1] — auto-wait vmcnt(24): retires B(kt),
//    which has had a full iteration of flight]
//   [cvt t -> aC(kt+1) — auto-wait vmcnt(8): retires A(kt+1), keeps B(kt+1)]
// A is converted f32->bf16 in-register (RNE, identical to prior prep pass) —
// no activation pre-conversion kernel at all.
__global__ __launch_bounds__(512, 1)
void gemm_reg(const float* __restrict__ A0, const float* __restrict__ A1,
              const __bf16* __restrict__ W0, const __bf16* __restrict__ W1,
              __bf16* __restrict__ C0, __bf16* __restrict__ C1)
{
    // XCD-aware bijective swizzle (256 blocks, 8 XCDs)
    const int b = blockIdx.x;
    const int swz = (b & 7) * 32 + (b >> 3);
    const int which = swz >> 7;
    const int r = swz & 127;
    const int bm = r >> 3, bn = r & 7;     // bm 0..15 (M/256), bn 0..7 (N/128)

    const float*  A = which ? A1 : A0;
    const __bf16* W = which ? W1 : W0;
    __bf16*       C = which ? C1 : C0;

    const int t = threadIdx.x;
    const int l = t & 63, w = t >> 6;
    const int wm = w >> 1, wn = w & 1;      // wave grid 4M x 2N, per-wave 64x64
    const int l15 = l & 15, lq = l >> 4;

    // per-fragment lane base offsets (element units)
    int idxA[4], idxB[4];
#pragma unroll
    for (int mi = 0; mi < 4; ++mi)
        idxA[mi] = (bm * 256 + wm * 64 + mi * 16 + l15) * KDIM + lq * 8;
#pragma unroll
    for (int ni = 0; ni < 4; ++ni)
        idxB[ni] = (bn * 128 + wn * 64 + ni * 16 + l15) * KDIM + lq * 8;

    const f32x4 zero4 = {0.f, 0.f, 0.f, 0.f};
    f32x4 acc[4][4];
#pragma unroll
    for (int mi = 0; mi < 4; ++mi)
#pragma unroll
        for (int ni = 0; ni < 4; ++ni) acc[mi][ni] = zero4;

    bf16x8 aC[2][4];        // current A fragments (bf16), overwritten per iter
    bf16x8 bF[2][2][4];     // B ping-pong [kt&1][kk][ni]
    f32x4  t0[2][4], t1[2][4];  // A f32 in-flight temps [kk][mi]

#define AISSUE(kt)                                                             \
    do {                                                                       \
        _Pragma("unroll")                                                      \
        for (int kk = 0; kk < 2; ++kk) {                                       \
            _Pragma("unroll")                                                  \
            for (int mi = 0; mi < 4; ++mi) {                                   \
                const f32x4* p = (const f32x4*)(A + idxA[mi] + (kt) * 64 + kk * 32); \
                t0[kk][mi] = p[0];                                             \
                t1[kk][mi] = p[1];                                             \
            }                                                                  \
        }                                                                      \
    } while (0)

#define BISSUE(pp, kt)                                                         \
    do {                                                                       \
        _Pragma("unroll")                                                      \
        for (int kk = 0; kk < 2; ++kk) {                                       \
            _Pragma("unroll")                                                  \
            for (int ni = 0; ni < 4; ++ni)                                     \
                bF[pp][kk][ni] = *(const bf16x8*)(W + idxB[ni] + (kt) * 64 + kk * 32); \
        }                                                                      \
    } while (0)

#define ACVT()                                                                 \
    do {                                                                       \
        _Pragma("unroll")                                                      \
        for (int kk = 0; kk < 2; ++kk) {                                       \
            _Pragma("unroll")                                                  \
            for (int mi = 0; mi < 4; ++mi) {                                   \
                bf16x8 v;                                                      \
                _Pragma("unroll")                                              \
                for (int i = 0; i < 4; ++i) {                                  \
                    v[i]     = (__bf16)t0[kk][mi][i];                          \
                    v[i + 4] = (__bf16)t1[kk][mi][i];                          \
                }                                                              \
                aC[kk][mi] = v;                                                \
            }                                                                  \
        }                                                                      \
    } while (0)

    // prologue: load + convert kt=0
    AISSUE(0);
    BISSUE(0, 0);
    ACVT();

#pragma unroll
    for (int kt = 0; kt < 16; ++kt) {
        if (kt < 15) {
            AISSUE(kt + 1);                 // 16 loads, in flight during MFMA
            BISSUE((kt + 1) & 1, kt + 1);   // 8 loads, full-iteration flight
        }

        __builtin_amdgcn_s_setprio(1);
#pragma unroll
        for (int kk = 0; kk < 2; ++kk)
#pragma unroll
            for (int mi = 0; mi < 4; ++mi)
#pragma unroll
                for (int ni = 0; ni < 4; ++ni)
                    acc[mi][ni] = __builtin_amdgcn_mfma_f32_16x16x32_bf16(
                        bF[kt & 1][kk][ni], aC[kk][mi], acc[mi][ni], 0, 0, 0);
        __builtin_amdgcn_s_setprio(0);

        if (kt < 15) ACVT();                // waits A(kt+1) only (vmcnt keeps B)
    }

    // C write (swapped-operand layout): batch = lane&15 (+mi*16),
    // feat = (lane>>4)*4 + rr (+ni*16); one 8B bf16x4 store per fragment
    const int batch0 = bm * 256 + wm * 64 + l15;
    const int feat0  = bn * 128 + wn * 64 + (lq << 2);
#pragma unroll
    for (int mi = 0; mi < 4; ++mi)
#pragma unroll
        for (int ni = 0; ni < 4; ++ni) {
            bf16x4 o;
#pragma unroll
            for (int rr = 0; rr < 4; ++rr) o[rr] = (__bf16)acc[mi][ni][rr];
            *(bf16x4*)(C + (size_t)(batch0 + mi * 16) * KDIM + feat0 + ni * 16) = o;
        }
#undef AISSUE
#undef BISSUE
#undef ACVT
}

// ---------------- fused scale+bias, LN(x), LN(h), tanh — one row per WAVE ----------------
__global__ __launch_bounds__(256)
void ln_tanh_k(const __bf16* __restrict__ X, const __bf16* __restrict__ Hh,
               const float* __restrict__ bi, const float* __restrict__ br,
               const float* __restrict__ scales, float* __restrict__ out)
{
    const int t = threadIdx.x;
    const int lane = t & 63, wid = t >> 6;
    const int row = blockIdx.x * 4 + wid;
    const float si = scales[0];
    const float sr = scales[1];

    const bf16x8* xp = (const bf16x8*)(X  + (size_t)row * 1024 + lane * 16);
    const bf16x8* hp = (const bf16x8*)(Hh + (size_t)row * 1024 + lane * 16);
    bf16x8 xv0 = xp[0], xv1 = xp[1];
    bf16x8 hv0 = hp[0], hv1 = hp[1];

    float xs[16], hs[16];
    float sx = 0.f, sh = 0.f;
#pragma unroll
    for (int q = 0; q < 4; ++q) {
        f32x4 bviq = ((const f32x4*)bi)[lane * 4 + q];
        f32x4 bvrq = ((const f32x4*)br)[lane * 4 + q];
#pragma unroll
        for (int j = 0; j < 4; ++j) {
            const int e = q * 4 + j;
            const float xf = (e < 8) ? (float)xv0[e] : (float)xv1[e - 8];
            const float hf = (e < 8) ? (float)hv0[e] : (float)hv1[e - 8];
            xs[e] = xf * si + bviq[j];
            hs[e] = hf * sr + bvrq[j];
            sx += xs[e]; sh += hs[e];
        }
    }

#pragma unroll
    for (int o = 32; o >= 1; o >>= 1) { sx += __shfl_xor(sx, o); sh += __shfl_xor(sh, o); }
    const float mx = sx * (1.0f / 1024.0f), mh = sh * (1.0f / 1024.0f);

    float vx = 0.f, vh = 0.f;
#pragma unroll
    for (int e = 0; e < 16; ++e) {
        xs[e] -= mx; hs[e] -= mh;
        vx += xs[e] * xs[e]; vh += hs[e] * hs[e];
    }
#pragma unroll
    for (int o = 32; o >= 1; o >>= 1) { vx += __shfl_xor(vx, o); vh += __shfl_xor(vh, o); }
    const float rsx = rsqrtf(vx * (1.0f / 1024.0f) + 1e-5f);
    const float rsh = rsqrtf(vh * (1.0f / 1024.0f) + 1e-5f);

    float* op = out + (size_t)row * 1024 + lane * 16;
#pragma unroll
    for (int q = 0; q < 4; ++q) {
        f32x4 o4;
#pragma unroll
        for (int j = 0; j < 4; ++j) {
            const int e = q * 4 + j;
            o4[j] = tanhf(xs[e] * rsx + hs[e] * rsh);
        }
        ((f32x4*)op)[q] = o4;
    }
}

extern "C" void kernel_launch(void* const* d_in, const int* in_sizes, int n_in,
                              void* d_out, int out_size, void* d_ws, size_t ws_size,
                              hipStream_t stream)
{
    const float* input_ = (const float*)d_in[0];
    const float* hidden = (const float*)d_in[1];
    const float* Wi     = (const float*)d_in[2];
    const float* bi     = (const float*)d_in[3];
    const float* Wr     = (const float*)d_in[4];
    const float* br     = (const float*)d_in[5];
    float* out = (float*)d_out;

    char* ws = (char*)d_ws;
    float* bmax   = (float*)ws;
    float* scales = (float*)(ws + 2048);
    __bf16* Qi = (__bf16*)(ws + 4096);
    __bf16* Qr = (__bf16*)(ws + 4096 + (1u << 21));
    __bf16* Xq = (__bf16*)(ws + 4096 + (2u << 21));
    __bf16* Hq = (__bf16*)(ws + 4096 + (2u << 21) + (1u << 23));

    absmax_k<<<512, 256, 0, stream>>>(Wi, Wr, bmax);
    quant_k<<<512, 256, 0, stream>>>(Wi, Wr, bmax, scales, Qi, Qr);
    gemm_reg<<<256, 512, 0, stream>>>(input_, hidden, Qi, Qr, Xq, Hq);
    ln_tanh_k<<<1024, 256, 0, stream>>>(Xq, Hq, bi, br, scales, out);
}

// Round 9
// 68.433 us; speedup vs baseline: 1.6582x; 1.6582x over previous
//
#include <hip/hip_runtime.h>
#include <hip/hip_bf16.h>

// Problem: B=4096, D_IN=D_H=K=1024.
//   x = input_ @ fq(Wi,4).T + bi ; h = hidden @ fq(Wr,4).T + br
//   out = tanh(LN(x) + LN(h))
// ws layout:
//   +0      : bmax f32[512] (per-block weight absmax; 0..255 Wi, 256..511 Wr)
//   +2048   : scales f32[2] (si, sr) written by quant_k
//   +4096   : Qi  bf16 ints, 2 MB
//   +2M+4096: Qr  bf16 ints, 2 MB
//   +4M+4096: Abf bf16, 8 MB
//   +12M+..: Hbf bf16, 8 MB
//   +20M+..: Xq  bf16 (x pre-LN, unscaled), 8 MB
//   +28M+..: Hq  bf16 (h pre-LN, unscaled), 8 MB

typedef float  f32x4  __attribute__((ext_vector_type(4)));
typedef __bf16 bf16x8 __attribute__((ext_vector_type(8)));
typedef __bf16 bf16x4 __attribute__((ext_vector_type(4)));

#define KDIM 1024

// ---------------- fused: weight absmax (blocks 0..511) + activation cvt (512..2559) ----------------
__global__ __launch_bounds__(256)
void prep1_k(const float* __restrict__ A, const float* __restrict__ Hh,
             const float* __restrict__ Wi, const float* __restrict__ Wr,
             float* __restrict__ bmax,
             __bf16* __restrict__ Abf, __bf16* __restrict__ Hbf)
{
    const int b = blockIdx.x, t = threadIdx.x;
    if (b < 512) {
        const int tensor = b >> 8;
        const float* W = tensor ? Wr : Wi;
        const int lane = t & 63, wid = t >> 6;
        const f32x4* p = (const f32x4*)W;
        const size_t base = (size_t)(b & 255) * 1024;
        float m = 0.f;
#pragma unroll
        for (int k = 0; k < 4; ++k) {
            f32x4 v = p[base + k * 256 + t];
            m = fmaxf(m, fmaxf(fmaxf(fabsf(v[0]), fabsf(v[1])),
                               fmaxf(fabsf(v[2]), fabsf(v[3]))));
        }
#pragma unroll
        for (int o = 32; o >= 1; o >>= 1) m = fmaxf(m, __shfl_xor(m, o));
        __shared__ float wm_[4];
        if (lane == 0) wm_[wid] = m;
        __syncthreads();
        if (t == 0) bmax[b] = fmaxf(fmaxf(wm_[0], wm_[1]), fmaxf(wm_[2], wm_[3]));
        return;
    }
    // activation f32 -> bf16
    const int c = b - 512;                       // 0..2047
    const float* src = (c < 1024) ? A : Hh;
    __bf16* dst = (c < 1024) ? Abf : Hbf;
    const int base = (c & 1023) * 4096;
#pragma unroll
    for (int j = 0; j < 2; ++j) {
        const int e = base + (j * 256 + t) * 8;
        f32x4 v0 = ((const f32x4*)(src + e))[0];
        f32x4 v1 = ((const f32x4*)(src + e))[1];
        bf16x8 o;
#pragma unroll
        for (int i = 0; i < 4; ++i) {
            o[i]     = (__bf16)v0[i];
            o[i + 4] = (__bf16)v1[i];
        }
        *(bf16x8*)(dst + e) = o;
    }
}

// ---------------- quantize weights to integer bf16 (reduces bmax per block) ----------------
__global__ __launch_bounds__(256)
void quant_k(const float* __restrict__ Wi, const float* __restrict__ Wr,
             const float* __restrict__ bmax, float* __restrict__ scales,
             __bf16* __restrict__ Qi, __bf16* __restrict__ Qr)
{
    const int tensor = blockIdx.x >> 8;
    const int b = blockIdx.x & 255;
    const int t = threadIdx.x;
    const int lane = t & 63, wid = t >> 6;

    float m = bmax[tensor * 256 + t];
#pragma unroll
    for (int o = 32; o >= 1; o >>= 1) m = fmaxf(m, __shfl_xor(m, o));
    __shared__ float wm_[4];
    if (lane == 0) wm_[wid] = m;
    __syncthreads();
    m = fmaxf(fmaxf(wm_[0], wm_[1]), fmaxf(wm_[2], wm_[3]));
    const float s = m / 7.0f;
    if (t == 0 && b == 0) scales[tensor] = s;

    const float* W = tensor ? Wr : Wi;
    __bf16* Q = tensor ? Qr : Qi;
#pragma unroll
    for (int j = 0; j < 2; ++j) {
        const int e = b * 4096 + (j * 256 + t) * 8;
        f32x4 v0 = ((const f32x4*)(W + e))[0];
        f32x4 v1 = ((const f32x4*)(W + e))[1];
        bf16x8 o;
#pragma unroll
        for (int i = 0; i < 4; ++i) {
            o[i]     = (__bf16)rintf(v0[i] / s);
            o[i + 4] = (__bf16)rintf(v1[i] / s);
        }
        *(bf16x8*)(Q + e) = o;
    }
}

// ---------------- dual bf16 MFMA GEMM: 128x128 tile, 4 waves, 2 blocks/CU ----------------
// A: bf16 (pre-converted), staged via global_load_lds into 3 LDS buffers
//    (16 KB each, 48 KB total -> 2 blocks/CU at grid 512), distance-2.
// B: quantized bf16 weights, global->reg direct (16B contiguous per lane,
//    L2-resident), distance-1 ping-pong regs. Bit-identical fragments to the
//    LDS path (verified round 6).
// __launch_bounds__(256,2) -> 256-VGPR cap: pipeline fits (rounds 6/8 failed
// under a hidden 128-VGPR cap that serialized the loads).
// vmcnt bookkeeping, ROBUST to intra-iteration reorder: each iter issues
// exactly 12 VMEM ops (4 A-DMA + 8 B-loads), so vmcnt(12) before the MFMA
// cluster retires ALL of the previous iteration's ops: A(kt+1) in LDS and
// B(kt) in regs. Tail: kt=14 issues 8 -> vmcnt(8); kt=15 issues 0 -> vmcnt(0).
// One s_barrier per iter. Buf overwrite (kt+2)%3 lands 2 barriers after its
// last reader (reads retire at each iter's lgkmcnt(0) before the barrier).
__global__ __launch_bounds__(256, 2)
void gemm_dual(const __bf16* __restrict__ A0, const __bf16* __restrict__ A1,
               const __bf16* __restrict__ W0, const __bf16* __restrict__ W1,
               __bf16* __restrict__ C0, __bf16* __restrict__ C1)
{
    __shared__ bf16x8 ldsA[3][1024];   // 48 KB: 128 rows x 64 k per buf

    // XCD-aware bijective swizzle (512 blocks, 8 XCDs)
    const int b = blockIdx.x;
    const int swz = (b & 7) * 64 + (b >> 3);
    const int which = swz >> 8;
    const int r = swz & 255;
    const int bm = r >> 3, bn = r & 7;   // bm 0..31 (M/128), bn 0..7 (N/128)

    const __bf16* A = which ? A1 : A0;
    const __bf16* W = which ? W1 : W0;
    __bf16*       C = which ? C1 : C0;

    const int t = threadIdx.x;
    const int l = t & 63, w = t >> 6;
    const int wm = w >> 1, wn = w & 1;   // wave grid 2M x 2N, per-wave 64x64
    const int l15 = l & 15, l7 = l & 7, lq = l >> 4;

    const __bf16* gA = A + (size_t)(bm * 128) * KDIM;
    const __bf16* gB = W + (size_t)(bn * 128) * KDIM;

    // A staging source offsets (element units), pre-swizzled for linear LDS
    int srcA[4];
#pragma unroll
    for (int j = 0; j < 4; ++j) {
        const int c = j * 256 + t;           // chunk 0..1023
        const int row = c >> 3, g = (c & 7) ^ (row & 7);
        srcA[j] = row * KDIM + g * 8;
    }

    // B fragment base pointers (kt/kk folded into <4KB immediate offsets)
    const __bf16* bptr[4];
#pragma unroll
    for (int ni = 0; ni < 4; ++ni)
        bptr[ni] = gB + (size_t)(wn * 64 + ni * 16 + l15) * KDIM + lq * 8;

#define STAGE(bb, kt)                                                          \
    do {                                                                       \
        _Pragma("unroll")                                                      \
        for (int j = 0; j < 4; ++j)                                            \
            __builtin_amdgcn_global_load_lds(                                  \
                (const __attribute__((address_space(1))) unsigned*)(gA + srcA[j] + (kt) * 64), \
                (__attribute__((address_space(3))) unsigned*)(&ldsA[bb][(j) * 256 + t]), \
                16, 0, 0);                                                     \
    } while (0)

#define BISSUE(pp, kt)                                                         \
    do {                                                                       \
        _Pragma("unroll")                                                      \
        for (int kk = 0; kk < 2; ++kk)                                         \
            _Pragma("unroll")                                                  \
            for (int ni = 0; ni < 4; ++ni)                                     \
                bF[pp][kk][ni] = *(const bf16x8*)(bptr[ni] + (kt) * 64 + kk * 32); \
    } while (0)

    const f32x4 zero4 = {0.f, 0.f, 0.f, 0.f};
    f32x4 acc[4][4];
#pragma unroll
    for (int mi = 0; mi < 4; ++mi)
#pragma unroll
        for (int ni = 0; ni < 4; ++ni) acc[mi][ni] = zero4;

    bf16x8 bF[2][2][4];   // ping-pong [kt&1][kk][ni], all indices static

    // prologue: A(0)->buf0, A(1)->buf1, B(0)->regs
    STAGE(0, 0);
    STAGE(1, 1);
    BISSUE(0, 0);
    asm volatile("s_waitcnt vmcnt(12)" ::: "memory");   // A(0) landed
    __builtin_amdgcn_s_barrier();

#pragma unroll
    for (int kt = 0; kt < 16; ++kt) {
        // ds_read A fragments of K-step kt
        const bf16x8* LA = &ldsA[kt % 3][0];
        bf16x8 af[2][4];
#pragma unroll
        for (int kk = 0; kk < 2; ++kk) {
            const int kq = kk * 4 + lq;
#pragma unroll
            for (int mi = 0; mi < 4; ++mi)
                af[kk][mi] = LA[(wm * 64 + mi * 16 + l15) * 8 + (kq ^ l7)];
        }

        // this iteration's VMEM issues: exactly 12 (4 DMA + 8 B) when kt<14
        if (kt < 14) STAGE((kt + 2) % 3, kt + 2);
        if (kt < 15) BISSUE((kt + 1) & 1, kt + 1);

        asm volatile("s_waitcnt lgkmcnt(0)" ::: "memory");   // af ready; bufA reads retired
        if (kt < 14)       { asm volatile("s_waitcnt vmcnt(12)" ::: "memory"); }
        else if (kt == 14) { asm volatile("s_waitcnt vmcnt(8)"  ::: "memory"); }
        else               { asm volatile("s_waitcnt vmcnt(0)"  ::: "memory"); }
        __builtin_amdgcn_sched_barrier(0);

        __builtin_amdgcn_s_setprio(1);
#pragma unroll
        for (int kk = 0; kk < 2; ++kk)
#pragma unroll
            for (int mi = 0; mi < 4; ++mi)
#pragma unroll
                for (int ni = 0; ni < 4; ++ni)
                    acc[mi][ni] = __builtin_amdgcn_mfma_f32_16x16x32_bf16(
                        bF[kt & 1][kk][ni], af[kk][mi], acc[mi][ni], 0, 0, 0);
        __builtin_amdgcn_s_setprio(0);

        if (kt < 15) __builtin_amdgcn_s_barrier();
    }

    // C write (swapped-operand layout): batch = lane&15 (+mi*16),
    // feat = (lane>>4)*4 + rr (+ni*16); one 8B bf16x4 store per fragment
    const int batch0 = bm * 128 + wm * 64 + l15;
    const int feat0  = bn * 128 + wn * 64 + (lq << 2);
#pragma unroll
    for (int mi = 0; mi < 4; ++mi)
#pragma unroll
        for (int ni = 0; ni < 4; ++ni) {
            bf16x4 o;
#pragma unroll
            for (int rr = 0; rr < 4; ++rr) o[rr] = (__bf16)acc[mi][ni][rr];
            *(bf16x4*)(C + (size_t)(batch0 + mi * 16) * KDIM + feat0 + ni * 16) = o;
        }
#undef STAGE
#undef BISSUE
}

// ---------------- fused scale+bias, LN(x), LN(h), tanh — one row per WAVE ----------------
__global__ __launch_bounds__(256)
void ln_tanh_k(const __bf16* __restrict__ X, const __bf16* __restrict__ Hh,
               const float* __restrict__ bi, const float* __restrict__ br,
               const float* __restrict__ scales, float* __restrict__ out)
{
    const int t = threadIdx.x;
    const int lane = t & 63, wid = t >> 6;
    const int row = blockIdx.x * 4 + wid;
    const float si = scales[0];
    const float sr = scales[1];

    const bf16x8* xp = (const bf16x8*)(X  + (size_t)row * 1024 + lane * 16);
    const bf16x8* hp = (const bf16x8*)(Hh + (size_t)row * 1024 + lane * 16);
    bf16x8 xv0 = xp[0], xv1 = xp[1];
    bf16x8 hv0 = hp[0], hv1 = hp[1];

    float xs[16], hs[16];
    float sx = 0.f, sh = 0.f;
#pragma unroll
    for (int q = 0; q < 4; ++q) {
        f32x4 bviq = ((const f32x4*)bi)[lane * 4 + q];
        f32x4 bvrq = ((const f32x4*)br)[lane * 4 + q];
#pragma unroll
        for (int j = 0; j < 4; ++j) {
            const int e = q * 4 + j;
            const float xf = (e < 8) ? (float)xv0[e] : (float)xv1[e - 8];
            const float hf = (e < 8) ? (float)hv0[e] : (float)hv1[e - 8];
            xs[e] = xf * si + bviq[j];
            hs[e] = hf * sr + bvrq[j];
            sx += xs[e]; sh += hs[e];
        }
    }

#pragma unroll
    for (int o = 32; o >= 1; o >>= 1) { sx += __shfl_xor(sx, o); sh += __shfl_xor(sh, o); }
    const float mx = sx * (1.0f / 1024.0f), mh = sh * (1.0f / 1024.0f);

    float vx = 0.f, vh = 0.f;
#pragma unroll
    for (int e = 0; e < 16; ++e) {
        xs[e] -= mx; hs[e] -= mh;
        vx += xs[e] * xs[e]; vh += hs[e] * hs[e];
    }
#pragma unroll
    for (int o = 32; o >= 1; o >>= 1) { vx += __shfl_xor(vx, o); vh += __shfl_xor(vh, o); }
    const float rsx = rsqrtf(vx * (1.0f / 1024.0f) + 1e-5f);
    const float rsh = rsqrtf(vh * (1.0f / 1024.0f) + 1e-5f);

    float* op = out + (size_t)row * 1024 + lane * 16;
#pragma unroll
    for (int q = 0; q < 4; ++q) {
        f32x4 o4;
#pragma unroll
        for (int j = 0; j < 4; ++j) {
            const int e = q * 4 + j;
            o4[j] = tanhf(xs[e] * rsx + hs[e] * rsh);
        }
        ((f32x4*)op)[q] = o4;
    }
}

extern "C" void kernel_launch(void* const* d_in, const int* in_sizes, int n_in,
                              void* d_out, int out_size, void* d_ws, size_t ws_size,
                              hipStream_t stream)
{
    const float* input_ = (const float*)d_in[0];
    const float* hidden = (const float*)d_in[1];
    const float* Wi     = (const float*)d_in[2];
    const float* bi     = (const float*)d_in[3];
    const float* Wr     = (const float*)d_in[4];
    const float* br     = (const float*)d_in[5];
    float* out = (float*)d_out;

    char* ws = (char*)d_ws;
    float* bmax   = (float*)ws;
    float* scales = (float*)(ws + 2048);
    __bf16* Qi  = (__bf16*)(ws + 4096);
    __bf16* Qr  = (__bf16*)(ws + 4096 + (1u << 21));
    __bf16* Abf = (__bf16*)(ws + 4096 + (2u << 21));
    __bf16* Hbf = (__bf16*)(ws + 4096 + (2u << 21) + (1u << 23));
    __bf16* Xq  = (__bf16*)(ws + 4096 + (2u << 21) + (2u << 23));
    __bf16* Hq  = (__bf16*)(ws + 4096 + (2u << 21) + (3u << 23));

    prep1_k<<<2560, 256, 0, stream>>>(input_, hidden, Wi, Wr, bmax, Abf, Hbf);
    quant_k<<<512, 256, 0, stream>>>(Wi, Wr, bmax, scales, Qi, Qr);
    gemm_dual<<<512, 256, 0, stream>>>(Abf, Hbf, Qi, Qr, Xq, Hq);
    ln_tanh_k<<<1024, 256, 0, stream>>>(Xq, Hq, bi, br, scales, out);
}

// Round 10
// 50.570 us; speedup vs baseline: 2.2439x; 1.3532x over previous
//
#include <hip/hip_runtime.h>
#include <hip/hip_bf16.h>

// Problem: B=4096, D_IN=D_H=K=1024.
//   x = input_ @ fq(Wi,4).T + bi ; h = hidden @ fq(Wr,4).T + br
//   out = tanh(LN(x) + LN(h))
// ws layout:
//   +0      : bmax f32[512]
//   +2048   : scales f32[2]
//   +4096   : Qi bf16 ints, 2 MB
//   +2M+4096: Qr bf16 ints, 2 MB
//   +4M+4096: Abf bf16, 8 MB
//   +12M+..: Hbf bf16, 8 MB
//   +20M+..: Xq bf16, 8 MB
//   +28M+..: Hq bf16, 8 MB

typedef float  f32x4  __attribute__((ext_vector_type(4)));
typedef __bf16 bf16x8 __attribute__((ext_vector_type(8)));
typedef __bf16 bf16x4 __attribute__((ext_vector_type(4)));

#define KDIM 1024

// ---------------- fused: weight absmax (blocks 0..511) + activation cvt (512..2559) ----------------
__global__ __launch_bounds__(256)
void prep1_k(const float* __restrict__ A, const float* __restrict__ Hh,
             const float* __restrict__ Wi, const float* __restrict__ Wr,
             float* __restrict__ bmax,
             __bf16* __restrict__ Abf, __bf16* __restrict__ Hbf)
{
    const int b = blockIdx.x, t = threadIdx.x;
    if (b < 512) {
        const int tensor = b >> 8;
        const float* W = tensor ? Wr : Wi;
        const int lane = t & 63, wid = t >> 6;
        const f32x4* p = (const f32x4*)W;
        const size_t base = (size_t)(b & 255) * 1024;
        float m = 0.f;
#pragma unroll
        for (int k = 0; k < 4; ++k) {
            f32x4 v = p[base + k * 256 + t];
            m = fmaxf(m, fmaxf(fmaxf(fabsf(v[0]), fabsf(v[1])),
                               fmaxf(fabsf(v[2]), fabsf(v[3]))));
        }
#pragma unroll
        for (int o = 32; o >= 1; o >>= 1) m = fmaxf(m, __shfl_xor(m, o));
        __shared__ float wm_[4];
        if (lane == 0) wm_[wid] = m;
        __syncthreads();
        if (t == 0) bmax[b] = fmaxf(fmaxf(wm_[0], wm_[1]), fmaxf(wm_[2], wm_[3]));
        return;
    }
    const int c = b - 512;
    const float* src = (c < 1024) ? A : Hh;
    __bf16* dst = (c < 1024) ? Abf : Hbf;
    const int base = (c & 1023) * 4096;
#pragma unroll
    for (int j = 0; j < 2; ++j) {
        const int e = base + (j * 256 + t) * 8;
        f32x4 v0 = ((const f32x4*)(src + e))[0];
        f32x4 v1 = ((const f32x4*)(src + e))[1];
        bf16x8 o;
#pragma unroll
        for (int i = 0; i < 4; ++i) {
            o[i]     = (__bf16)v0[i];
            o[i + 4] = (__bf16)v1[i];
        }
        *(bf16x8*)(dst + e) = o;
    }
}

// ---------------- quantize weights to integer bf16 ----------------
__global__ __launch_bounds__(256)
void quant_k(const float* __restrict__ Wi, const float* __restrict__ Wr,
             const float* __restrict__ bmax, float* __restrict__ scales,
             __bf16* __restrict__ Qi, __bf16* __restrict__ Qr)
{
    const int tensor = blockIdx.x >> 8;
    const int b = blockIdx.x & 255;
    const int t = threadIdx.x;
    const int lane = t & 63, wid = t >> 6;

    float m = bmax[tensor * 256 + t];
#pragma unroll
    for (int o = 32; o >= 1; o >>= 1) m = fmaxf(m, __shfl_xor(m, o));
    __shared__ float wm_[4];
    if (lane == 0) wm_[wid] = m;
    __syncthreads();
    m = fmaxf(fmaxf(wm_[0], wm_[1]), fmaxf(wm_[2], wm_[3]));
    const float s = m / 7.0f;
    if (t == 0 && b == 0) scales[tensor] = s;

    const float* W = tensor ? Wr : Wi;
    __bf16* Q = tensor ? Qr : Qi;
#pragma unroll
    for (int j = 0; j < 2; ++j) {
        const int e = b * 4096 + (j * 256 + t) * 8;
        f32x4 v0 = ((const f32x4*)(W + e))[0];
        f32x4 v1 = ((const f32x4*)(W + e))[1];
        bf16x8 o;
#pragma unroll
        for (int i = 0; i < 4; ++i) {
            o[i]     = (__bf16)rintf(v0[i] / s);
            o[i + 4] = (__bf16)rintf(v1[i] / s);
        }
        *(bf16x8*)(Q + e) = o;
    }
}

// ---------------- dual bf16 MFMA GEMM: 256x128, 8 waves (2Mx4N), 4-PHASE schedule ----------------
// T3/T4 port of the m201 8-phase template at this tile. vs round 5, ONLY the
// phase granularity changes: per K-tile, 4 phases of
//   {4-8 ds_read | 2 global_load_lds stage -> s_barrier -> lgkmcnt(0) ->
//    setprio(1) 8 MFMA setprio(0) -> s_barrier}
// vmcnt(6) once per K-tile (phase 3, certifies kt+1; kt+2's 6 loads stay in
// flight; kt=14 -> vmcnt(0) tail). 3 LDS buffers, distance-2 staging.
// Per-wave output 128x32 (acc[8][2]); fragment bytes, K-order and C mapping
// identical to round 5 => bit-identical output.
__global__ __launch_bounds__(512, 2)
void gemm_dual(const __bf16* __restrict__ A0, const __bf16* __restrict__ A1,
               const __bf16* __restrict__ W0, const __bf16* __restrict__ W1,
               __bf16* __restrict__ C0, __bf16* __restrict__ C1)
{
    __shared__ bf16x8 lds[3][3072];   // [buf][A:0..2047 | B:2048..3071] = 144 KB

    // XCD-aware bijective swizzle (256 blocks, 8 XCDs)
    const int b = blockIdx.x;
    const int swz = (b & 7) * 32 + (b >> 3);
    const int which = swz >> 7;
    const int r = swz & 127;
    const int bm = r >> 3, bn = r & 7;     // bm 0..15 (M/256), bn 0..7 (N/128)

    const __bf16* A = which ? A1 : A0;
    const __bf16* W = which ? W1 : W0;
    __bf16*       C = which ? C1 : C0;

    const int t = threadIdx.x;
    const int l = t & 63, w = t >> 6;
    const int wm = w >> 2, wn = w & 3;      // 2M x 4N, per-wave 128 x 32
    const int l15 = l & 15, l7 = l & 7, lq = l >> 4;

    const __bf16* gA = A + (size_t)(bm * 256) * KDIM;
    const __bf16* gB = W + (size_t)(bn * 128) * KDIM;

    // staging source offsets (element units), pre-swizzled for linear LDS
    int srcA[4], srcB[2];
#pragma unroll
    for (int j = 0; j < 4; ++j) {
        const int c = j * 512 + t;          // A chunk 0..2047 (row 0..255)
        const int row = c >> 3, g = (c & 7) ^ (row & 7);
        srcA[j] = row * KDIM + g * 8;
    }
#pragma unroll
    for (int j = 0; j < 2; ++j) {
        const int c = j * 512 + t;          // B chunk 0..1023 (row 0..127)
        const int row = c >> 3, g = (c & 7) ^ (row & 7);
        srcB[j] = row * KDIM + g * 8;
    }

#define GLA(bb, j, kt)                                                         \
    __builtin_amdgcn_global_load_lds(                                          \
        (const __attribute__((address_space(1))) unsigned*)(gA + srcA[j] + (kt) * 64), \
        (__attribute__((address_space(3))) unsigned*)(&lds[bb][(j) * 512 + t]),\
        16, 0, 0)
#define GLB(bb, j, kt)                                                         \
    __builtin_amdgcn_global_load_lds(                                          \
        (const __attribute__((address_space(1))) unsigned*)(gB + srcB[j] + (kt) * 64), \
        (__attribute__((address_space(3))) unsigned*)(&lds[bb][2048 + (j) * 512 + t]), \
        16, 0, 0)

    f32x4 acc[8][2];
#pragma unroll
    for (int mi = 0; mi < 8; ++mi)
#pragma unroll
        for (int ni = 0; ni < 2; ++ni) acc[mi][ni] = (f32x4){0.f, 0.f, 0.f, 0.f};

    // A-fragment read for quadrant q (mi = q*2 + j), B-fragment read
#define AREAD(q)                                                               \
    do {                                                                       \
        _Pragma("unroll")                                                      \
        for (int j = 0; j < 2; ++j)                                            \
            _Pragma("unroll")                                                  \
            for (int kk = 0; kk < 2; ++kk)                                     \
                af[j][kk] = LA[(wm * 128 + ((q) * 2 + j) * 16 + l15) * 8 +     \
                               (((kk * 4 + lq) ^ l7))];                        \
    } while (0)

#define MFMA8(q)                                                               \
    do {                                                                       \
        __builtin_amdgcn_s_setprio(1);                                         \
        _Pragma("unroll")                                                      \
        for (int kk = 0; kk < 2; ++kk)                                         \
            _Pragma("unroll")                                                  \
            for (int j = 0; j < 2; ++j)                                        \
                _Pragma("unroll")                                              \
                for (int ni = 0; ni < 2; ++ni)                                 \
                    acc[(q) * 2 + j][ni] = __builtin_amdgcn_mfma_f32_16x16x32_bf16( \
                        bfv[ni][kk], af[j][kk], acc[(q) * 2 + j][ni], 0, 0, 0);\
        __builtin_amdgcn_s_setprio(0);                                         \
    } while (0)

#define BAR()    __builtin_amdgcn_s_barrier()
#define LGKM0()  do { asm volatile("s_waitcnt lgkmcnt(0)" ::: "memory");       \
                      __builtin_amdgcn_sched_barrier(0); } while (0)

    // prologue: stage kt=0 -> buf0, kt=1 -> buf1
    GLA(0, 0, 0); GLA(0, 1, 0); GLA(0, 2, 0); GLA(0, 3, 0);
    GLB(0, 0, 0); GLB(0, 1, 0);
    GLA(1, 0, 1); GLA(1, 1, 1); GLA(1, 2, 1); GLA(1, 3, 1);
    GLB(1, 0, 1); GLB(1, 1, 1);
    asm volatile("s_waitcnt vmcnt(6)" ::: "memory");   // buf0 landed
    BAR();

    int cur = 0, nx2 = 2;
    for (int kt = 0; kt < 16; ++kt) {
        const bf16x8* LA = &lds[cur][0];
        const bf16x8* LB = &lds[cur][2048];
        bf16x8 af[2][2], bfv[2][2];

        // ---- phase 0: B frags + A q0 | stage A01(kt+2) ----
#pragma unroll
        for (int ni = 0; ni < 2; ++ni)
#pragma unroll
            for (int kk = 0; kk < 2; ++kk)
                bfv[ni][kk] = LB[(wn * 32 + ni * 16 + l15) * 8 + ((kk * 4 + lq) ^ l7)];
        AREAD(0);
        if (kt < 14) { GLA(nx2, 0, kt + 2); GLA(nx2, 1, kt + 2); }
        BAR(); LGKM0();
        MFMA8(0);
        BAR();

        // ---- phase 1: A q1 | stage A23(kt+2) ----
        AREAD(1);
        if (kt < 14) { GLA(nx2, 2, kt + 2); GLA(nx2, 3, kt + 2); }
        BAR(); LGKM0();
        MFMA8(1);
        BAR();

        // ---- phase 2: A q2 | stage B01(kt+2) ----
        AREAD(2);
        if (kt < 14) { GLB(nx2, 0, kt + 2); GLB(nx2, 1, kt + 2); }
        BAR(); LGKM0();
        MFMA8(2);
        BAR();

        // ---- phase 3: A q3 | vmcnt certify kt+1 ----
        AREAD(3);
        if (kt < 14)       { asm volatile("s_waitcnt vmcnt(6)" ::: "memory"); }
        else if (kt == 14) { asm volatile("s_waitcnt vmcnt(0)" ::: "memory"); }
        BAR(); LGKM0();
        MFMA8(3);
        if (kt < 15) BAR();

        cur = (cur == 2) ? 0 : cur + 1;
        nx2 = (nx2 == 2) ? 0 : nx2 + 1;
    }

    // C write (swapped-operand layout): batch = lane&15 (+mi*16),
    // feat = (lane>>4)*4 + rr (+ni*16)
    const int batch0 = bm * 256 + wm * 128 + l15;
    const int feat0  = bn * 128 + wn * 32 + (lq << 2);
#pragma unroll
    for (int mi = 0; mi < 8; ++mi)
#pragma unroll
        for (int ni = 0; ni < 2; ++ni) {
            bf16x4 o;
#pragma unroll
            for (int rr = 0; rr < 4; ++rr) o[rr] = (__bf16)acc[mi][ni][rr];
            *(bf16x4*)(C + (size_t)(batch0 + mi * 16) * KDIM + feat0 + ni * 16) = o;
        }
#undef GLA
#undef GLB
#undef AREAD
#undef MFMA8
#undef BAR
#undef LGKM0
}

// ---------------- fused scale+bias, LN(x), LN(h), tanh — one row per WAVE ----------------
__global__ __launch_bounds__(256)
void ln_tanh_k(const __bf16* __restrict__ X, const __bf16* __restrict__ Hh,
               const float* __restrict__ bi, const float* __restrict__ br,
               const float* __restrict__ scales, float* __restrict__ out)
{
    const int t = threadIdx.x;
    const int lane = t & 63, wid = t >> 6;
    const int row = blockIdx.x * 4 + wid;
    const float si = scales[0];
    const float sr = scales[1];

    const bf16x8* xp = (const bf16x8*)(X  + (size_t)row * 1024 + lane * 16);
    const bf16x8* hp = (const bf16x8*)(Hh + (size_t)row * 1024 + lane * 16);
    bf16x8 xv0 = xp[0], xv1 = xp[1];
    bf16x8 hv0 = hp[0], hv1 = hp[1];

    float xs[16], hs[16];
    float sx = 0.f, sh = 0.f;
#pragma unroll
    for (int q = 0; q < 4; ++q) {
        f32x4 bviq = ((const f32x4*)bi)[lane * 4 + q];
        f32x4 bvrq = ((const f32x4*)br)[lane * 4 + q];
#pragma unroll
        for (int j = 0; j < 4; ++j) {
            const int e = q * 4 + j;
            const float xf = (e < 8) ? (float)xv0[e] : (float)xv1[e - 8];
            const float hf = (e < 8) ? (float)hv0[e] : (float)hv1[e - 8];
            xs[e] = xf * si + bviq[j];
            hs[e] = hf * sr + bvrq[j];
            sx += xs[e]; sh += hs[e];
        }
    }

#pragma unroll
    for (int o = 32; o >= 1; o >>= 1) { sx += __shfl_xor(sx, o); sh += __shfl_xor(sh, o); }
    const float mx = sx * (1.0f / 1024.0f), mh = sh * (1.0f / 1024.0f);

    float vx = 0.f, vh = 0.f;
#pragma unroll
    for (int e = 0; e < 16; ++e) {
        xs[e] -= mx; hs[e] -= mh;
        vx += xs[e] * xs[e]; vh += hs[e] * hs[e];
    }
#pragma unroll
    for (int o = 32; o >= 1; o >>= 1) { vx += __shfl_xor(vx, o); vh += __shfl_xor(vh, o); }
    const float rsx = rsqrtf(vx * (1.0f / 1024.0f) + 1e-5f);
    const float rsh = rsqrtf(vh * (1.0f / 1024.0f) + 1e-5f);

    float* op = out + (size_t)row * 1024 + lane * 16;
#pragma unroll
    for (int q = 0; q < 4; ++q) {
        f32x4 o4;
#pragma unroll
        for (int j = 0; j < 4; ++j) {
            const int e = q * 4 + j;
            o4[j] = tanhf(xs[e] * rsx + hs[e] * rsh);
        }
        ((f32x4*)op)[q] = o4;
    }
}

extern "C" void kernel_launch(void* const* d_in, const int* in_sizes, int n_in,
                              void* d_out, int out_size, void* d_ws, size_t ws_size,
                              hipStream_t stream)
{
    const float* input_ = (const float*)d_in[0];
    const float* hidden = (const float*)d_in[1];
    const float* Wi     = (const float*)d_in[2];
    const float* bi     = (const float*)d_in[3];
    const float* Wr     = (const float*)d_in[4];
    const float* br     = (const float*)d_in[5];
    float* out = (float*)d_out;

    char* ws = (char*)d_ws;
    float* bmax   = (float*)ws;
    float* scales = (float*)(ws + 2048);
    __bf16* Qi  = (__bf16*)(ws + 4096);
    __bf16* Qr  = (__bf16*)(ws + 4096 + (1u << 21));
    __bf16* Abf = (__bf16*)(ws + 4096 + (2u << 21));
    __bf16* Hbf = (__bf16*)(ws + 4096 + (2u << 21) + (1u << 23));
    __bf16* Xq  = (__bf16*)(ws + 4096 + (2u << 21) + (2u << 23));
    __bf16* Hq  = (__bf16*)(ws + 4096 + (2u << 21) + (3u << 23));

    prep1_k<<<2560, 256, 0, stream>>>(input_, hidden, Wi, Wr, bmax, Abf, Hbf);
    quant_k<<<512, 256, 0, stream>>>(Wi, Wr, bmax, scales, Qi, Qr);
    gemm_dual<<<256, 512, 0, stream>>>(Abf, Hbf, Qi, Qr, Xq, Hq);
    ln_tanh_k<<<1024, 256, 0, stream>>>(Xq, Hq, bi, br, scales, out);
}

// Round 11
// 47.972 us; speedup vs baseline: 2.3654x; 1.0542x over previous
//
#include <hip/hip_runtime.h>
#include <hip/hip_bf16.h>

// Problem: B=4096, D_IN=D_H=K=1024.
//   x = input_ @ fq(Wi,4).T + bi ; h = hidden @ fq(Wr,4).T + br
//   out = tanh(LN(x) + LN(h))
// ws layout:
//   +0      : bmax f32[512]
//   +2048   : scales f32[2]
//   +4096   : Qi bf16 ints, 2 MB
//   +2M+4096: Qr bf16 ints, 2 MB
//   +4M+4096: Abf bf16, 8 MB
//   +12M+..: Hbf bf16, 8 MB
//   +20M+..: Xq bf16, 8 MB
//   +28M+..: Hq bf16, 8 MB

typedef float  f32x4  __attribute__((ext_vector_type(4)));
typedef __bf16 bf16x8 __attribute__((ext_vector_type(8)));
typedef __bf16 bf16x4 __attribute__((ext_vector_type(4)));

#define KDIM 1024

// ---------------- fused: weight absmax (blocks 0..511) + activation cvt (512..2559) ----------------
__global__ __launch_bounds__(256)
void prep1_k(const float* __restrict__ A, const float* __restrict__ Hh,
             const float* __restrict__ Wi, const float* __restrict__ Wr,
             float* __restrict__ bmax,
             __bf16* __restrict__ Abf, __bf16* __restrict__ Hbf)
{
    const int b = blockIdx.x, t = threadIdx.x;
    if (b < 512) {
        const int tensor = b >> 8;
        const float* W = tensor ? Wr : Wi;
        const int lane = t & 63, wid = t >> 6;
        const f32x4* p = (const f32x4*)W;
        const size_t base = (size_t)(b & 255) * 1024;
        float m = 0.f;
#pragma unroll
        for (int k = 0; k < 4; ++k) {
            f32x4 v = p[base + k * 256 + t];
            m = fmaxf(m, fmaxf(fmaxf(fabsf(v[0]), fabsf(v[1])),
                               fmaxf(fabsf(v[2]), fabsf(v[3]))));
        }
#pragma unroll
        for (int o = 32; o >= 1; o >>= 1) m = fmaxf(m, __shfl_xor(m, o));
        __shared__ float wm_[4];
        if (lane == 0) wm_[wid] = m;
        __syncthreads();
        if (t == 0) bmax[b] = fmaxf(fmaxf(wm_[0], wm_[1]), fmaxf(wm_[2], wm_[3]));
        return;
    }
    const int c = b - 512;
    const float* src = (c < 1024) ? A : Hh;
    __bf16* dst = (c < 1024) ? Abf : Hbf;
    const int base = (c & 1023) * 4096;
#pragma unroll
    for (int j = 0; j < 2; ++j) {
        const int e = base + (j * 256 + t) * 8;
        f32x4 v0 = ((const f32x4*)(src + e))[0];
        f32x4 v1 = ((const f32x4*)(src + e))[1];
        bf16x8 o;
#pragma unroll
        for (int i = 0; i < 4; ++i) {
            o[i]     = (__bf16)v0[i];
            o[i + 4] = (__bf16)v1[i];
        }
        *(bf16x8*)(dst + e) = o;
    }
}

// ---------------- quantize weights to integer bf16 ----------------
__global__ __launch_bounds__(256)
void quant_k(const float* __restrict__ Wi, const float* __restrict__ Wr,
             const float* __restrict__ bmax, float* __restrict__ scales,
             __bf16* __restrict__ Qi, __bf16* __restrict__ Qr)
{
    const int tensor = blockIdx.x >> 8;
    const int b = blockIdx.x & 255;
    const int t = threadIdx.x;
    const int lane = t & 63, wid = t >> 6;

    float m = bmax[tensor * 256 + t];
#pragma unroll
    for (int o = 32; o >= 1; o >>= 1) m = fmaxf(m, __shfl_xor(m, o));
    __shared__ float wm_[4];
    if (lane == 0) wm_[wid] = m;
    __syncthreads();
    m = fmaxf(fmaxf(wm_[0], wm_[1]), fmaxf(wm_[2], wm_[3]));
    const float s = m / 7.0f;
    if (t == 0 && b == 0) scales[tensor] = s;

    const float* W = tensor ? Wr : Wi;
    __bf16* Q = tensor ? Qr : Qi;
#pragma unroll
    for (int j = 0; j < 2; ++j) {
        const int e = b * 4096 + (j * 256 + t) * 8;
        f32x4 v0 = ((const f32x4*)(W + e))[0];
        f32x4 v1 = ((const f32x4*)(W + e))[1];
        bf16x8 o;
#pragma unroll
        for (int i = 0; i < 4; ++i) {
            o[i]     = (__bf16)rintf(v0[i] / s);
            o[i + 4] = (__bf16)rintf(v1[i] / s);
        }
        *(bf16x8*)(Q + e) = o;
    }
}

// ---------------- dual bf16 MFMA GEMM: 256x128, 8 waves, CROSS-ITERATION PIPELINE ----------------
// Round-5 shell (3-buf DMA staging, 1 barrier/iter, same fragment bytes &
// K-order => bit-identical output). New: iteration kt's 16 ds_reads are
// issued during iteration kt-1 into the alternate register bank, in two
// ordered groups (bfv0+af0 | bfv1+af1) pinned by sched_barrier(0).
// Iteration kt:
//   lgkm(8)  -> group1 of reads(kt) landed     -> 16 MFMA (kk=0)
//   lgkm(0)  -> group2 landed
//   vmcnt(0) -> certifies buf kt+1 (only stage(kt+1), issued iter kt-1,
//               is outstanding at this point; stage(kt+2) not yet issued)
//   s_barrier
//   STAGE(kt+2) (6 gll, vmcnt-only) ; issue reads(kt+1) -> bank^1
//   16 MFMA (kk=1)    [hides the read/DMA issue + starts their latency]
// Overwrite proof: reads of buf (kt-1)%3 retired at iter kt-1's lgkm(0),
// >=1 barrier before STAGE(kt+2) rewrites it. Rule-#18 sched_barrier(0)
// after every counted wait.
__global__ __launch_bounds__(512, 2)
void gemm_dual(const __bf16* __restrict__ A0, const __bf16* __restrict__ A1,
               const __bf16* __restrict__ W0, const __bf16* __restrict__ W1,
               __bf16* __restrict__ C0, __bf16* __restrict__ C1)
{
    __shared__ bf16x8 lds[3][3072];   // [buf][A:0..2047 | B:2048..3071] = 144 KB

    // XCD-aware bijective swizzle (256 blocks, 8 XCDs)
    const int b = blockIdx.x;
    const int swz = (b & 7) * 32 + (b >> 3);
    const int which = swz >> 7;
    const int r = swz & 127;
    const int bm = r >> 3, bn = r & 7;     // bm 0..15 (M/256), bn 0..7 (N/128)

    const __bf16* A = which ? A1 : A0;
    const __bf16* W = which ? W1 : W0;
    __bf16*       C = which ? C1 : C0;

    const int t = threadIdx.x;
    const int l = t & 63, w = t >> 6;
    const int wm = w >> 1, wn = w & 1;      // wave grid 4M x 2N, per-wave 64x64
    const int l15 = l & 15, l7 = l & 7, lq = l >> 4;

    const __bf16* gA = A + (size_t)(bm * 256) * KDIM;
    const __bf16* gB = W + (size_t)(bn * 128) * KDIM;

    // staging source offsets (element units), pre-swizzled for linear LDS
    int srcA[4], srcB[2];
#pragma unroll
    for (int j = 0; j < 4; ++j) {
        const int c = j * 512 + t;
        const int row = c >> 3, g = (c & 7) ^ (row & 7);
        srcA[j] = row * KDIM + g * 8;
    }
#pragma unroll
    for (int j = 0; j < 2; ++j) {
        const int c = j * 512 + t;
        const int row = c >> 3, g = (c & 7) ^ (row & 7);
        srcB[j] = row * KDIM + g * 8;
    }

#define STAGE(bb, kt)                                                          \
    do {                                                                       \
        _Pragma("unroll")                                                      \
        for (int j = 0; j < 4; ++j)                                            \
            __builtin_amdgcn_global_load_lds(                                  \
                (const __attribute__((address_space(1))) unsigned*)(gA + srcA[j] + (kt) * 64), \
                (__attribute__((address_space(3))) unsigned*)(&lds[bb][(j) * 512 + t]), \
                16, 0, 0);                                                     \
        _Pragma("unroll")                                                      \
        for (int j = 0; j < 2; ++j)                                            \
            __builtin_amdgcn_global_load_lds(                                  \
                (const __attribute__((address_space(1))) unsigned*)(gB + srcB[j] + (kt) * 64), \
                (__attribute__((address_space(3))) unsigned*)(&lds[bb][2048 + (j) * 512 + t]), \
                16, 0, 0);                                                     \
    } while (0)

    // fragment LDS chunk offsets [kk][idx]
    int offA[2][4], offB[2][4];
#pragma unroll
    for (int kk = 0; kk < 2; ++kk) {
        const int kq = kk * 4 + lq;
#pragma unroll
        for (int mi = 0; mi < 4; ++mi)
            offA[kk][mi] = (wm * 64 + mi * 16 + l15) * 8 + (kq ^ l7);
#pragma unroll
        for (int ni = 0; ni < 4; ++ni)
            offB[kk][ni] = (wn * 64 + ni * 16 + l15) * 8 + (kq ^ l7);
    }

    f32x4 acc[4][4];
#pragma unroll
    for (int mi = 0; mi < 4; ++mi)
#pragma unroll
        for (int ni = 0; ni < 4; ++ni) acc[mi][ni] = (f32x4){0.f, 0.f, 0.f, 0.f};

    bf16x8 afb[2][2][4], bfvb[2][2][4];   // [bank][kk][idx], static idx

    // issue reads for buffer bufi into bank bk: group1 (kk=0), SB, group2 (kk=1), SB
#define READS(bk, bufi)                                                        \
    do {                                                                       \
        const bf16x8* LA_ = &lds[bufi][0];                                     \
        const bf16x8* LB_ = &lds[bufi][2048];                                  \
        _Pragma("unroll")                                                      \
        for (int ni = 0; ni < 4; ++ni) bfvb[bk][0][ni] = LB_[offB[0][ni]];     \
        _Pragma("unroll")                                                      \
        for (int mi = 0; mi < 4; ++mi) afb[bk][0][mi]  = LA_[offA[0][mi]];     \
        __builtin_amdgcn_sched_barrier(0);                                     \
        _Pragma("unroll")                                                      \
        for (int ni = 0; ni < 4; ++ni) bfvb[bk][1][ni] = LB_[offB[1][ni]];     \
        _Pragma("unroll")                                                      \
        for (int mi = 0; mi < 4; ++mi) afb[bk][1][mi]  = LA_[offA[1][mi]];     \
        __builtin_amdgcn_sched_barrier(0);                                     \
    } while (0)

#define MFMA16(bk, kk)                                                         \
    do {                                                                       \
        __builtin_amdgcn_s_setprio(1);                                         \
        _Pragma("unroll")                                                      \
        for (int mi = 0; mi < 4; ++mi)                                         \
            _Pragma("unroll")                                                  \
            for (int ni = 0; ni < 4; ++ni)                                     \
                acc[mi][ni] = __builtin_amdgcn_mfma_f32_16x16x32_bf16(         \
                    bfvb[bk][kk][ni], afb[bk][kk][mi], acc[mi][ni], 0, 0, 0);  \
        __builtin_amdgcn_s_setprio(0);                                         \
    } while (0)

#define LGKM(n)                                                                \
    do { asm volatile("s_waitcnt lgkmcnt(" #n ")" ::: "memory");               \
         __builtin_amdgcn_sched_barrier(0); } while (0)

    // prologue: stage kt=0 -> buf0, kt=1 -> buf1; certify buf0; issue reads(0)
    STAGE(0, 0);
    STAGE(1, 1);
    asm volatile("s_waitcnt vmcnt(6)" ::: "memory");   // buf0 landed
    __builtin_amdgcn_s_barrier();
    READS(0, 0);

#pragma unroll
    for (int kt = 0; kt < 16; ++kt) {
        const int bk = kt & 1;

        LGKM(8);                 // group1 of reads(kt) landed
        MFMA16(bk, 0);
        LGKM(0);                 // group2 landed; all reads of buf kt retired

        if (kt < 15) {
            asm volatile("s_waitcnt vmcnt(0)" ::: "memory");   // buf kt+1 certified
            __builtin_amdgcn_sched_barrier(0);
            __builtin_amdgcn_s_barrier();
            if (kt < 14) STAGE((kt + 2) % 3, kt + 2);
            READS(bk ^ 1, (kt + 1) % 3);
        }

        MFMA16(bk, 1);           // hides the read/DMA issue just made
    }

    // C write (swapped-operand layout): batch = lane&15 (+mi*16),
    // feat = (lane>>4)*4 + rr (+ni*16); one 8B bf16x4 store per fragment
    const int batch0 = bm * 256 + wm * 64 + l15;
    const int feat0  = bn * 128 + wn * 64 + (lq << 2);
#pragma unroll
    for (int mi = 0; mi < 4; ++mi)
#pragma unroll
        for (int ni = 0; ni < 4; ++ni) {
            bf16x4 o;
#pragma unroll
            for (int rr = 0; rr < 4; ++rr) o[rr] = (__bf16)acc[mi][ni][rr];
            *(bf16x4*)(C + (size_t)(batch0 + mi * 16) * KDIM + feat0 + ni * 16) = o;
        }
#undef STAGE
#undef READS
#undef MFMA16
#undef LGKM
}

// ---------------- fused scale+bias, LN(x), LN(h), tanh — one row per WAVE ----------------
__global__ __launch_bounds__(256)
void ln_tanh_k(const __bf16* __restrict__ X, const __bf16* __restrict__ Hh,
               const float* __restrict__ bi, const float* __restrict__ br,
               const float* __restrict__ scales, float* __restrict__ out)
{
    const int t = threadIdx.x;
    const int lane = t & 63, wid = t >> 6;
    const int row = blockIdx.x * 4 + wid;
    const float si = scales[0];
    const float sr = scales[1];

    const bf16x8* xp = (const bf16x8*)(X  + (size_t)row * 1024 + lane * 16);
    const bf16x8* hp = (const bf16x8*)(Hh + (size_t)row * 1024 + lane * 16);
    bf16x8 xv0 = xp[0], xv1 = xp[1];
    bf16x8 hv0 = hp[0], hv1 = hp[1];

    float xs[16], hs[16];
    float sx = 0.f, sh = 0.f;
#pragma unroll
    for (int q = 0; q < 4; ++q) {
        f32x4 bviq = ((const f32x4*)bi)[lane * 4 + q];
        f32x4 bvrq = ((const f32x4*)br)[lane * 4 + q];
#pragma unroll
        for (int j = 0; j < 4; ++j) {
            const int e = q * 4 + j;
            const float xf = (e < 8) ? (float)xv0[e] : (float)xv1[e - 8];
            const float hf = (e < 8) ? (float)hv0[e] : (float)hv1[e - 8];
            xs[e] = xf * si + bviq[j];
            hs[e] = hf * sr + bvrq[j];
            sx += xs[e]; sh += hs[e];
        }
    }

#pragma unroll
    for (int o = 32; o >= 1; o >>= 1) { sx += __shfl_xor(sx, o); sh += __shfl_xor(sh, o); }
    const float mx = sx * (1.0f / 1024.0f), mh = sh * (1.0f / 1024.0f);

    float vx = 0.f, vh = 0.f;
#pragma unroll
    for (int e = 0; e < 16; ++e) {
        xs[e] -= mx; hs[e] -= mh;
        vx += xs[e] * xs[e]; vh += hs[e] * hs[e];
    }
#pragma unroll
    for (int o = 32; o >= 1; o >>= 1) { vx += __shfl_xor(vx, o); vh += __shfl_xor(vh, o); }
    const float rsx = rsqrtf(vx * (1.0f / 1024.0f) + 1e-5f);
    const float rsh = rsqrtf(vh * (1.0f / 1024.0f) + 1e-5f);

    float* op = out + (size_t)row * 1024 + lane * 16;
#pragma unroll
    for (int q = 0; q < 4; ++q) {
        f32x4 o4;
#pragma unroll
        for (int j = 0; j < 4; ++j) {
            const int e = q * 4 + j;
            o4[j] = tanhf(xs[e] * rsx + hs[e] * rsh);
        }
        ((f32x4*)op)[q] = o4;
    }
}

extern "C" void kernel_launch(void* const* d_in, const int* in_sizes, int n_in,
                              void* d_out, int out_size, void* d_ws, size_t ws_size,
                              hipStream_t stream)
{
    const float* input_ = (const float*)d_in[0];
    const float* hidden = (const float*)d_in[1];
    const float* Wi     = (const float*)d_in[2];
    const float* bi     = (const float*)d_in[3];
    const float* Wr     = (const float*)d_in[4];
    const float* br     = (const float*)d_in[5];
    float* out = (float*)d_out;

    char* ws = (char*)d_ws;
    float* bmax   = (float*)ws;
    float* scales = (float*)(ws + 2048);
    __bf16* Qi  = (__bf16*)(ws + 4096);
    __bf16* Qr  = (__bf16*)(ws + 4096 + (1u << 21));
    __bf16* Abf = (__bf16*)(ws + 4096 + (2u << 21));
    __bf16* Hbf = (__bf16*)(ws + 4096 + (2u << 21) + (1u << 23));
    __bf16* Xq  = (__bf16*)(ws + 4096 + (2u << 21) + (2u << 23));
    __bf16* Hq  = (__bf16*)(ws + 4096 + (2u << 21) + (3u << 23));

    prep1_k<<<2560, 256, 0, stream>>>(input_, hidden, Wi, Wr, bmax, Abf, Hbf);
    quant_k<<<512, 256, 0, stream>>>(Wi, Wr, bmax, scales, Qi, Qr);
    gemm_dual<<<256, 512, 0, stream>>>(Abf, Hbf, Qi, Qr, Xq, Hq);
    ln_tanh_k<<<1024, 256, 0, stream>>>(Xq, Hq, bi, br, scales, out);
}